// Round 7
// baseline (77798.236 us; speedup 1.0000x reference)
//
#include <hip/hip_runtime.h>

// Problem constants
#define NB   128
#define LSEQ 2048
#define HID  512
#define EMB  256
#define KD   768
// Tiling: 256 blocks = 2 n-groups x 128 h-blocks (HT=4 -> 16 gate-rows/block)
// 512 threads = 64 n  x  8 kseg (wave-uniform k-split)
// Each thread: ONE n, ALL 16 gate-rows, k-range = 64 H-k + 32 E-j.
#define NGR   2
#define HBL   128
#define NWG   256
#define NTHR  512
#define HN    (HID*NB)       // one H buffer (65536 floats)
#define RING  4

#define AT_RLX __ATOMIC_RELAXED
#define SCOPE  __HIP_MEMORY_SCOPE_AGENT

__device__ __forceinline__ float sigf(float x) { return 1.0f / (1.0f + __expf(-x)); }
__device__ __forceinline__ float tanhfast(float x) { return fmaf(-2.0f, 1.0f / (1.0f + __expf(2.0f * x)), 1.0f); }

__global__ void __launch_bounds__(NTHR, 2)
lstm_pers(const int* __restrict__ X, const float* __restrict__ E,
          const float* __restrict__ Ww, const float* __restrict__ Wb,
          float* __restrict__ out, float* __restrict__ ws)
{
    const int tid = threadIdx.x;
    const int bid = blockIdx.x;
    const int nb  = bid & (NGR - 1);           // n-group 0..1
    const int hb  = bid >> 1;                  // h-block 0..127
    const int nl  = tid & 63;                  // n within group
    const int ng  = nb * 64 + nl;              // global n
    const int h0  = hb * 4;                    // h-tile base
    // wave-uniform k-segment (forced into SGPR so W loads scalarize to s_load)
    const int kseg = __builtin_amdgcn_readfirstlane(tid >> 6);  // 0..7
    const int kb  = kseg * 64;                 // H-part k base   [kb, kb+64)
    const int jb  = kseg * 32;                 // E-part j base   [jb, jb+32)

    __shared__ float red[7][16][64];           // 28,672 B (SoA, conflict-free b32)

    float* Hring = ws;                          // RING * HN floats (1 MB)
    int*   flags = (int*)(ws + RING * HN);      // [nb][HBL] per-block epoch flags

    // 16 wave-uniform W row pointers (rows: gate g, h0+hh), SGPR-resident
    const float* Wr[16];
    #pragma unroll
    for (int g = 0; g < 4; ++g)
        #pragma unroll
        for (int hh = 0; hh < 4; ++hh)
            Wr[g * 4 + hh] = Ww + (size_t)(g * HID + h0 + hh) * KD;

    // ---- zero H(0) (ring slot 0): kseg-0 wave, bypass stores ----
    if (kseg == 0) {
        #pragma unroll
        for (int hh = 0; hh < 4; ++hh)
            __hip_atomic_store(&Hring[(h0 + hh) * NB + ng], 0.0f, AT_RLX, SCOPE);
    }
    float bF[4] = {0,0,0,0}, bI[4] = {0,0,0,0}, bO[4] = {0,0,0,0}, bT[4] = {0,0,0,0};
    float cc[4] = {0,0,0,0};                   // cell state (kseg-0 threads)
    if (kseg == 0) {
        #pragma unroll
        for (int hh = 0; hh < 4; ++hh) {
            bF[hh] = Wb[0 * HID + h0 + hh];
            bI[hh] = Wb[1 * HID + h0 + hh];
            bO[hh] = Wb[2 * HID + h0 + hh];
            bT[hh] = Wb[3 * HID + h0 + hh];
        }
    }

    // syncthreads drains vmcnt(0) (zero-stores ack'd at LLC) before the flag.
    // flags start poisoned 0xAAAAAAAA (negative int) -> signed compares work.
    __syncthreads();
    if (tid == 0) __hip_atomic_store(&flags[nb * HBL + hb], 0, AT_RLX, SCOPE);

    for (int t = 0; t < LSEQ; ++t) {
        float acc[16];
        #pragma unroll
        for (int i = 0; i < 16; ++i) acc[i] = 0.0f;

        // ---- E-part first (cached reads, no H dependency; hides producer tail) ----
        {
            int x = X[ng * LSEQ + t];
            const float* er = E + (size_t)x * EMB + jb;
            #pragma unroll
            for (int j4 = 0; j4 < 8; ++j4) {
                float4 m = *(const float4*)(er + j4 * 4);
                #pragma unroll
                for (int r = 0; r < 16; ++r) {
                    float4 w = *(const float4*)(Wr[r] + HID + jb + j4 * 4); // s_load (uniform)
                    acc[r] = fmaf(w.x, m.x, fmaf(w.y, m.y, fmaf(w.z, m.z, fmaf(w.w, m.w, acc[r]))));
                }
            }
        }

        // ---- poll: threads 0..127 each watch ONE flag of our n-group ----
        if (tid < HBL) {
            const int* fp = flags + nb * HBL + tid;
            while (__hip_atomic_load(fp, AT_RLX, SCOPE) < t)
                __builtin_amdgcn_s_sleep(1);
        }
        __syncthreads();

        const float* Hc = Hring + (t & (RING - 1)) * HN;
        float*       Hw = Hring + ((t + 1) & (RING - 1)) * HN;

        // ---- H-part: 64 k's, UNIQUE bypass loads, batched 16-deep for latency ----
        #pragma unroll
        for (int ch = 0; ch < 4; ++ch) {
            float hv[16];
            #pragma unroll
            for (int j = 0; j < 16; ++j)          // 16 loads issue back-to-back
                hv[j] = __hip_atomic_load(&Hc[(kb + ch * 16 + j) * NB + ng], AT_RLX, SCOPE);
            #pragma unroll
            for (int j4 = 0; j4 < 4; ++j4) {
                #pragma unroll
                for (int r = 0; r < 16; ++r) {
                    float4 w = *(const float4*)(Wr[r] + kb + ch * 16 + j4 * 4); // s_load
                    acc[r] = fmaf(w.x, hv[j4 * 4 + 0],
                             fmaf(w.y, hv[j4 * 4 + 1],
                             fmaf(w.z, hv[j4 * 4 + 2],
                             fmaf(w.w, hv[j4 * 4 + 3], acc[r]))));
                }
            }
        }

        // ---- cross-kseg reduction (8 -> 1): one LDS stage, conflict-free b32 ----
        if (kseg != 0) {
            #pragma unroll
            for (int c = 0; c < 16; ++c) red[kseg - 1][c][nl] = acc[c];
        }
        __syncthreads();
        if (kseg == 0) {
            #pragma unroll
            for (int s = 0; s < 7; ++s)
                #pragma unroll
                for (int c = 0; c < 16; ++c) acc[c] += red[s][c][nl];

            // ---- gates + state update + H publish (this thread owns all 4 h's) ----
            #pragma unroll
            for (int hh = 0; hh < 4; ++hh) {
                float F = sigf(acc[0 * 4 + hh] + bF[hh]);
                float I = sigf(acc[1 * 4 + hh] + bI[hh]);
                float O = sigf(acc[2 * 4 + hh] + bO[hh]);
                float T = tanhfast(acc[3 * 4 + hh] + bT[hh]);
                cc[hh] = fmaf(F, cc[hh], I * T);
                float hvn = O * tanhfast(cc[hh]);
                __hip_atomic_store(&Hw[(h0 + hh) * NB + ng], hvn, AT_RLX, SCOPE);
                if (t == LSEQ - 1)
                    __hip_atomic_store(&out[(size_t)ng * HID + h0 + hh], hvn, AT_RLX, SCOPE);
            }
        }

        // syncthreads drains every wave's vmcnt(0): h-stores ack'd at the LLC
        // before tid0's relaxed flag store -> consumers that see the flag read
        // fresh H via bypass loads. No acquire/release/invalidate anywhere.
        __syncthreads();
        if (tid == 0)
            __hip_atomic_store(&flags[nb * HBL + hb], t + 1, AT_RLX, SCOPE);
    }
}

extern "C" void kernel_launch(void* const* d_in, const int* in_sizes, int n_in,
                              void* d_out, int out_size, void* d_ws, size_t ws_size,
                              hipStream_t stream) {
    const int*   X   = (const int*)d_in[0];
    const float* E   = (const float*)d_in[1];
    const float* Ww  = (const float*)d_in[2];
    const float* Wb  = (const float*)d_in[3];
    float*       out = (float*)d_out;
    float*       ws  = (float*)d_ws;
    void* args[] = { (void*)&X, (void*)&E, (void*)&Ww, (void*)&Wb, (void*)&out, (void*)&ws };
    hipError_t e = hipLaunchCooperativeKernel((const void*)lstm_pers, dim3(NWG), dim3(NTHR),
                                              args, 0, stream);
    if (e != hipSuccess) {
        // 256 blocks, 28.7KB LDS -> >=1 block/CU, all co-resident on idle 256-CU chip.
        hipLaunchKernelGGL(lstm_pers, dim3(NWG), dim3(NTHR), 0, stream,
                           X, E, Ww, Wb, out, ws);
    }
}

// Round 8
// 39711.130 us; speedup vs baseline: 1.9591x; 1.9591x over previous
//
#include <hip/hip_runtime.h>

// Problem constants
#define NB   128
#define LSEQ 2048
#define HID  512
#define EMB  256
#define KD   768
// Tiling: 256 blocks = 2 n-groups x 128 h-blocks (4 h each)
// 512 threads = 16 nq (4 n's) x 4 hl x 8 kseg
// Thread: 4 gate-rows of h=h0+hl, 4 n's, K-slice of 96 (64 H-k + 32 E-j).
#define NGR   2
#define HBL   128
#define NWG   256
#define NTHR  512
#define WSTR  772            // W row stride: 772%32=4 -> 4 hl rows on disjoint bank quads
#define HN    (HID*NB)       // one H buffer (65536 floats)
#define RING  4

#define AT_RLX __ATOMIC_RELAXED
#define AT_ACQ __ATOMIC_ACQUIRE
#define SCOPE  __HIP_MEMORY_SCOPE_AGENT

__device__ __forceinline__ void fma4(float4& a, const float4& v, float s) {
    a.x = fmaf(s, v.x, a.x); a.y = fmaf(s, v.y, a.y);
    a.z = fmaf(s, v.z, a.z); a.w = fmaf(s, v.w, a.w);
}
__device__ __forceinline__ void add4(float4& a, const float4& b) {
    a.x += b.x; a.y += b.y; a.z += b.z; a.w += b.w;
}
__device__ __forceinline__ float dot4(const float4& w, const float4& m) {
    return fmaf(w.x, m.x, fmaf(w.y, m.y, fmaf(w.z, m.z, w.w * m.w)));
}
__device__ __forceinline__ float sigf(float x) { return 1.0f / (1.0f + __expf(-x)); }
__device__ __forceinline__ float tanhfast(float x) { return fmaf(-2.0f, 1.0f / (1.0f + __expf(2.0f * x)), 1.0f); }
__device__ __forceinline__ unsigned long long f2u(float2 f) {
    union { unsigned long long u; float2 f; } c; c.f = f; return c.u;
}

__global__ void __launch_bounds__(NTHR, 2)
lstm_pers(const int* __restrict__ X, const float* __restrict__ E,
          const float* __restrict__ Ww, const float* __restrict__ Wb,
          float* __restrict__ out, float* __restrict__ ws)
{
    const int tid  = threadIdx.x;
    const int bid  = blockIdx.x;
    const int nb   = bid & (NGR - 1);          // n-group 0..1
    const int hb   = bid >> 1;                 // h-block 0..127
    const int nq   = tid & 15;                 // n-quad index (4 n's)
    const int hl   = (tid >> 4) & 3;           // h within block
    const int kseg = tid >> 6;                 // 0..7, wave-uniform
    const int lid  = tid & 63;                 // (nq,hl) id within wave pattern
    const int n0   = nb * 64 + nq * 4;         // global n (4 consecutive)
    const int hg   = hb * 4 + hl;              // global h
    const int h0   = hb * 4;

    __shared__ float  Wl[16 * WSTR];           // 49,408 B
    __shared__ float4 red[7][4][64];           // 28,672 B (slot, gate, lid)

    float* Hring = ws;                          // RING * HN floats (1 MB)
    int*   flags = (int*)(ws + RING * HN);      // [nb][HBL] per-block epoch flags

    // ---- stage W slice into LDS (16 rows: g*4+h) ----
    for (int i = tid; i < 16 * (KD / 4); i += NTHR) {
        int r = i / (KD / 4), c4 = i - r * (KD / 4);
        int g = r >> 2, h = r & 3;
        float4 v = *((const float4*)(Ww + (size_t)(g * HID + h0 + h) * KD) + c4);
        *(float4*)(Wl + r * WSTR + c4 * 4) = v;
    }
    // ---- zero H(0) (ring slot 0): kseg-0 wave, bypass stores (2x 8B) ----
    if (kseg == 0) {
        __hip_atomic_store((unsigned long long*)&Hring[hg * NB + n0],     0ull, AT_RLX, SCOPE);
        __hip_atomic_store((unsigned long long*)&Hring[hg * NB + n0 + 2], 0ull, AT_RLX, SCOPE);
    }
    float bF = 0, bI = 0, bO = 0, bT = 0;
    float cc0 = 0, cc1 = 0, cc2 = 0, cc3 = 0;   // cell state for 4 n's (kseg-0)
    if (kseg == 0) {
        bF = Wb[0 * HID + hg]; bI = Wb[1 * HID + hg];
        bO = Wb[2 * HID + hg]; bT = Wb[3 * HID + hg];
    }

    // syncthreads drains vmcnt(0) (zero-stores ack'd at LLC) before the flag.
    // flags start poisoned 0xAAAAAAAA (negative int) -> signed compares work.
    __syncthreads();
    if (tid == 0) __hip_atomic_store(&flags[nb * HBL + hb], 0, AT_RLX, SCOPE);

    const float* Wr0 = Wl + (0 * 4 + hl) * WSTR;   // F row of h
    const float* Wr1 = Wl + (1 * 4 + hl) * WSTR;   // I
    const float* Wr2 = Wl + (2 * 4 + hl) * WSTR;   // O
    const float* Wr3 = Wl + (3 * 4 + hl) * WSTR;   // T
    const int kb = kseg * 64;                   // H-part k base
    const int jb = kseg * 32;                   // E-part j base
    const int nq_g = nb * 16 + nq;              // float4 column in H row (NB/4=32)

    for (int t = 0; t < LSEQ; ++t) {
        float4 a0 = {0,0,0,0}, a1 = {0,0,0,0}, a2 = {0,0,0,0}, a3 = {0,0,0,0};

        // ---- E-part first (cached, no H dependency; hides producer tail).
        // Lanes sharing nq (4 hl's, same wave) read identical addresses ->
        // wave-level broadcast, unique L1/L2 traffic.
        {
            int x0 = X[(n0 + 0) * LSEQ + t];
            int x1 = X[(n0 + 1) * LSEQ + t];
            int x2 = X[(n0 + 2) * LSEQ + t];
            int x3 = X[(n0 + 3) * LSEQ + t];
            const float* e0 = E + (size_t)x0 * EMB + jb;
            const float* e1 = E + (size_t)x1 * EMB + jb;
            const float* e2 = E + (size_t)x2 * EMB + jb;
            const float* e3 = E + (size_t)x3 * EMB + jb;
            #pragma unroll
            for (int j4 = 0; j4 < 8; ++j4) {
                int j = j4 * 4;
                float4 m0 = *(const float4*)(e0 + j);
                float4 m1 = *(const float4*)(e1 + j);
                float4 m2 = *(const float4*)(e2 + j);
                float4 m3 = *(const float4*)(e3 + j);
                float4 w0 = *(const float4*)(Wr0 + HID + jb + j);  // LDS, 16-lane bcast
                float4 w1 = *(const float4*)(Wr1 + HID + jb + j);
                float4 w2 = *(const float4*)(Wr2 + HID + jb + j);
                float4 w3 = *(const float4*)(Wr3 + HID + jb + j);
                a0.x += dot4(w0, m0); a0.y += dot4(w0, m1); a0.z += dot4(w0, m2); a0.w += dot4(w0, m3);
                a1.x += dot4(w1, m0); a1.y += dot4(w1, m1); a1.z += dot4(w1, m2); a1.w += dot4(w1, m3);
                a2.x += dot4(w2, m0); a2.y += dot4(w2, m1); a2.z += dot4(w2, m2); a2.w += dot4(w2, m3);
                a3.x += dot4(w3, m0); a3.y += dot4(w3, m1); a3.z += dot4(w3, m2); a3.w += dot4(w3, m3);
            }
        }

        // ---- poll: threads 0..127 each watch ONE flag of our n-group ----
        if (tid < HBL) {
            const int* fp = flags + nb * HBL + tid;
            while (__hip_atomic_load(fp, AT_RLX, SCOPE) < t)
                __builtin_amdgcn_s_sleep(1);
            // Every RING steps: acquire -> buffer_inv (L1+L2). Slot-t lines were
            // last cached RING steps ago; exactly one inv lands in between, so
            // the cached H reads below always refill fresh from LLC (where the
            // producer's bypass stores live). W is LDS-resident: unaffected.
            if ((t & (RING - 1)) == 0)
                (void)__hip_atomic_load(fp, AT_ACQ, SCOPE);
        }
        __syncthreads();   // orders inv before all waves' H loads

        const float4* Hc4 = (const float4*)(Hring + (t & (RING - 1)) * HN);
        float*        Hw  = Hring + ((t + 1) & (RING - 1)) * HN;

        // ---- H-part: 64 k's. Cached float4 loads; 4 hl-lanes broadcast. ----
        #pragma unroll 4
        for (int kk = 0; kk < 64; kk += 4) {
            int k = kb + kk;
            float4 h0 = Hc4[(k + 0) * (NB / 4) + nq_g];
            float4 h1 = Hc4[(k + 1) * (NB / 4) + nq_g];
            float4 h2 = Hc4[(k + 2) * (NB / 4) + nq_g];
            float4 h3 = Hc4[(k + 3) * (NB / 4) + nq_g];
            float4 w0 = *(const float4*)(Wr0 + k);
            float4 w1 = *(const float4*)(Wr1 + k);
            float4 w2 = *(const float4*)(Wr2 + k);
            float4 w3 = *(const float4*)(Wr3 + k);
            fma4(a0, h0, w0.x); fma4(a0, h1, w0.y); fma4(a0, h2, w0.z); fma4(a0, h3, w0.w);
            fma4(a1, h0, w1.x); fma4(a1, h1, w1.y); fma4(a1, h2, w1.z); fma4(a1, h3, w1.w);
            fma4(a2, h0, w2.x); fma4(a2, h1, w2.y); fma4(a2, h2, w2.z); fma4(a2, h3, w2.w);
            fma4(a3, h0, w3.x); fma4(a3, h1, w3.y); fma4(a3, h2, w3.z); fma4(a3, h3, w3.w);
        }

        // ---- cross-kseg reduction (8 -> 1): single stage, one sync ----
        if (kseg != 0) {
            red[kseg - 1][0][lid] = a0; red[kseg - 1][1][lid] = a1;
            red[kseg - 1][2][lid] = a2; red[kseg - 1][3][lid] = a3;
        }
        __syncthreads();
        if (kseg == 0) {
            #pragma unroll
            for (int s = 0; s < 7; ++s) {
                add4(a0, red[s][0][lid]); add4(a1, red[s][1][lid]);
                add4(a2, red[s][2][lid]); add4(a3, red[s][3][lid]);
            }
            // ---- gates + state + H publish (h fixed, 4 n's) ----
            float F, I, O, T, v0, v1, v2, v3;
            F = sigf(a0.x + bF); I = sigf(a1.x + bI); O = sigf(a2.x + bO); T = tanhfast(a3.x + bT);
            cc0 = fmaf(F, cc0, I * T); v0 = O * tanhfast(cc0);
            F = sigf(a0.y + bF); I = sigf(a1.y + bI); O = sigf(a2.y + bO); T = tanhfast(a3.y + bT);
            cc1 = fmaf(F, cc1, I * T); v1 = O * tanhfast(cc1);
            F = sigf(a0.z + bF); I = sigf(a1.z + bI); O = sigf(a2.z + bO); T = tanhfast(a3.z + bT);
            cc2 = fmaf(F, cc2, I * T); v2 = O * tanhfast(cc2);
            F = sigf(a0.w + bF); I = sigf(a1.w + bI); O = sigf(a2.w + bO); T = tanhfast(a3.w + bT);
            cc3 = fmaf(F, cc3, I * T); v3 = O * tanhfast(cc3);
            __hip_atomic_store((unsigned long long*)&Hw[hg * NB + n0],
                               f2u(make_float2(v0, v1)), AT_RLX, SCOPE);
            __hip_atomic_store((unsigned long long*)&Hw[hg * NB + n0 + 2],
                               f2u(make_float2(v2, v3)), AT_RLX, SCOPE);
            if (t == LSEQ - 1) {
                __hip_atomic_store(&out[(size_t)(n0 + 0) * HID + hg], v0, AT_RLX, SCOPE);
                __hip_atomic_store(&out[(size_t)(n0 + 1) * HID + hg], v1, AT_RLX, SCOPE);
                __hip_atomic_store(&out[(size_t)(n0 + 2) * HID + hg], v2, AT_RLX, SCOPE);
                __hip_atomic_store(&out[(size_t)(n0 + 3) * HID + hg], v3, AT_RLX, SCOPE);
            }
        }

        // syncthreads drains vmcnt(0): h-stores ack'd at LLC before the flag.
        __syncthreads();
        if (tid == 0)
            __hip_atomic_store(&flags[nb * HBL + hb], t + 1, AT_RLX, SCOPE);
    }
}

extern "C" void kernel_launch(void* const* d_in, const int* in_sizes, int n_in,
                              void* d_out, int out_size, void* d_ws, size_t ws_size,
                              hipStream_t stream) {
    const int*   X   = (const int*)d_in[0];
    const float* E   = (const float*)d_in[1];
    const float* Ww  = (const float*)d_in[2];
    const float* Wb  = (const float*)d_in[3];
    float*       out = (float*)d_out;
    float*       ws  = (float*)d_ws;
    void* args[] = { (void*)&X, (void*)&E, (void*)&Ww, (void*)&Wb, (void*)&out, (void*)&ws };
    hipError_t e = hipLaunchCooperativeKernel((const void*)lstm_pers, dim3(NWG), dim3(NTHR),
                                              args, 0, stream);
    if (e != hipSuccess) {
        // 256 blocks, 78KB LDS -> 1 block/CU, all co-resident on idle 256-CU chip.
        hipLaunchKernelGGL(lstm_pers, dim3(NWG), dim3(NTHR), 0, stream,
                           X, E, Ww, Wb, out, ws);
    }
}